// Round 3
// baseline (359.659 us; speedup 1.0000x reference)
//
#include <hip/hip_runtime.h>

// Light-field per-pixel 9x9 filter, R3.
// out[b,s,o,h,w] = clip(sum_{i,ky,kx} lf[b,s,i,3h-3+ky,3w-3+kx] * W[s,o,i,h,w,81] + bias, 0, 1)
//
// R2 was latency-bound (hbm 23%, VALU 7%, occ 28%): per-phase global_load_lds +
// barrier drained vmcnt(0) -> exposed HBM round-trip x9, LDS 41.5KB -> 3 blk/CU.
// R3: block = (w:64)x(b:4), weight slice 20.7KB single-buffered in LDS,
// T14 register prefetch (load next phase's slice to regs during current compute,
// ds_write after barrier) -> stage latency hidden; 7 blk/CU LDS-wise.

#define ST 9
#define INC 3
#define OUTC 3
#define OHH 128
#define OWW 128
#define KDIM 9
#define KK 81
#define HH 384
#define WW 384
#define HWSZ (HH*WW)          // 147456
#define SLICE (64*KK)         // 5184 floats per (s,o,i,h,w-half)
#define NPH (INC*OUTC)        // 9 phases

__global__ __launch_bounds__(256, 5) void lf_filter_kernel(
    const float* __restrict__ lf, const float* __restrict__ wts,
    const float* __restrict__ bias, float* __restrict__ out)
{
  __shared__ float ldsW[SLICE];   // 20736 B -> up to 7 blocks/CU

  const int t   = threadIdx.x;
  const int wl  = t & 63;          // w within half
  const int b   = t >> 6;          // batch (one per wave)
  const int bid = blockIdx.x;
  const int wh  = bid & 1;         // w half
  const int h   = (bid >> 1) & 127;
  const int s   = bid >> 8;
  const int w   = wh*64 + wl;
  const int xbase = 3*w - 3;
  const int ybase = 3*h - 3;

  const float* lfb = lf + (size_t)(b*ST + s)*INC*HWSZ;

  // per-thread clamped x indices + validity masks (constant across phases;
  // static-indexed under full unroll -> stays in VGPRs)
  int   xi[KDIM];
  float xm[KDIM];
  #pragma unroll
  for (int kx = 0; kx < KDIM; ++kx) {
    const int x = xbase + kx;
    xi[kx] = x < 0 ? 0 : (x > WW-1 ? WW-1 : x);
    xm[kx] = ((unsigned)x < (unsigned)WW) ? 1.f : 0.f;
  }

  float acc[OUTC] = {0.f, 0.f, 0.f};

  // prologue: prefetch phase 0 weight slice into regs (1296 float4 / block)
  float4 pre[5]; float4 pre5;
  {
    const float4* ws4 = (const float4*)(wts +
        ((size_t)(((s*OUTC + 0)*INC + 0)*OHH + h)*OWW + 64*wh)*KK);
    #pragma unroll
    for (int j = 0; j < 5; ++j) pre[j] = ws4[j*256 + t];
    if (t < 16) pre5 = ws4[1280 + t];
  }

  #pragma unroll
  for (int p = 0; p < NPH; ++p) {
    const int i = p / OUTC, o = p % OUTC;

    __syncthreads();                       // everyone done reading ldsW (phase p-1)
    // commit prefetched slice to LDS
    {
      float4* ld4 = (float4*)ldsW;
      #pragma unroll
      for (int j = 0; j < 5; ++j) ld4[j*256 + t] = pre[j];
      if (t < 16) ld4[1280 + t] = pre5;
    }
    // issue next phase's prefetch (in flight during compute below)
    if (p + 1 < NPH) {
      const int i2 = (p+1) / OUTC, o2 = (p+1) % OUTC;
      const float4* ws4 = (const float4*)(wts +
          ((size_t)(((s*OUTC + o2)*INC + i2)*OHH + h)*OWW + 64*wh)*KK);
      #pragma unroll
      for (int j = 0; j < 5; ++j) pre[j] = ws4[j*256 + t];
      if (t < 16) pre5 = ws4[1280 + t];
    }
    __syncthreads();                       // ldsW ready

    // ---- compute phase p: 81 taps from LDS weights + global lf ----
    const float* lfr = lfb + (size_t)i*HWSZ;
    float a = acc[o];
    #pragma unroll
    for (int ky = 0; ky < KDIM; ++ky) {
      const int y = ybase + ky;            // block-uniform -> scalar branch
      if ((unsigned)y < (unsigned)HH) {
        const float* rowp = lfr + (size_t)y*WW;
        #pragma unroll
        for (int kx = 0; kx < KDIM; ++kx) {
          const float wv = ldsW[wl*KK + ky*KDIM + kx];  // lane stride 81: conflict-free
          const float v  = rowp[xi[kx]] * xm[kx];       // clamped+masked edge handling
          a = fmaf(v, wv, a);
        }
      }
    }
    acc[o] = a;
  }

  // ---- epilogue: bias + clip + coalesced stores ----
  #pragma unroll
  for (int o = 0; o < OUTC; ++o) {
    const float bv = bias[((s*OUTC + o)*OHH + h)*OWW + w];
    float r = acc[o] + bv;
    r = r < 0.f ? 0.f : (r > 1.f ? 1.f : r);
    out[(((size_t)(b*ST + s)*OUTC + o)*OHH + h)*OWW + w] = r;
  }
}

extern "C" void kernel_launch(void* const* d_in, const int* in_sizes, int n_in,
                              void* d_out, int out_size, void* d_ws, size_t ws_size,
                              hipStream_t stream) {
  const float* lf   = (const float*)d_in[0];
  const float* wts  = (const float*)d_in[1];
  const float* bias = (const float*)d_in[2];
  float* out = (float*)d_out;
  dim3 grid(ST * OHH * 2);   // 2304 blocks: (s, h, w-half)
  dim3 block(256);           // (w:64) x (batch:4)
  hipLaunchKernelGGL(lf_filter_kernel, grid, block, 0, stream, lf, wts, bias, out);
}

// Round 4
// 193.925 us; speedup vs baseline: 1.8546x; 1.8546x over previous
//
#include <hip/hip_runtime.h>

// Light-field per-pixel 9x9 filter, R4.
// out[b,s,o,h,w] = clip(sum_{i,ky,kx} lf[b,s,i,3h-3+ky,3w-3+kx] * W[s,o,i,h,w,81] + bias, 0, 1)
//
// R3 post-mortem: reg-prefetch + __launch_bounds__(256,5) => VGPR cap 48 => the
// prefetch spilled to scratch (WRITE_SIZE 7->405 MB). R4: double-buffered LDS
// staged with global_load_lds (zero VGPR cost), issue-next -> compute-current ->
// barrier; stage latency hides under the 81-tap compute. Small blocks (128 thr,
// 32w x 4b, 20.7 KB LDS dbuf) => 7 blocks/CU = 14 waves, 7 HBM streams/CU.

#define ST 9
#define INC 3
#define OUTC 3
#define OHH 128
#define OWW 128
#define KDIM 9
#define KK 81
#define HH 384
#define WW 384
#define HWSZ (HH*WW)          // 147456
#define WQ 32                 // w columns per block
#define SLICE (WQ*KK)         // 2592 floats = 10368 B per (s,o,i,h,w-quarter)
#define NPH (INC*OUTC)        // 9 phases

__device__ __forceinline__ void gll16(const float* g, float* l) {
  __builtin_amdgcn_global_load_lds((const __attribute__((address_space(1))) void*)g,
                                   (__attribute__((address_space(3))) void*)l, 16, 0, 0);
}

__global__ __launch_bounds__(128) void lf_filter_kernel(
    const float* __restrict__ lf, const float* __restrict__ wts,
    const float* __restrict__ bias, float* __restrict__ out)
{
  __shared__ float ldsW[2][SLICE];   // 20736 B total -> 7 blocks/CU

  const int t   = threadIdx.x;
  const int wl  = t & 31;           // w within quarter
  const int b   = t >> 5;           // batch (half-wave each)
  const int bid = blockIdx.x;
  const int wq  = bid & 3;          // w quarter
  const int h   = (bid >> 2) & 127;
  const int s   = bid >> 9;
  const int w   = wq*WQ + wl;
  const int xbase = 3*w - 3;
  const int ybase = 3*h - 3;

  const float* lfb = lf + (size_t)(b*ST + s)*INC*HWSZ;

  // clamped x indices + masks (static-indexed under unroll -> VGPRs)
  int   xi[KDIM];
  float xm[KDIM];
  #pragma unroll
  for (int kx = 0; kx < KDIM; ++kx) {
    const int x = xbase + kx;
    xi[kx] = x < 0 ? 0 : (x > WW-1 ? WW-1 : x);
    xm[kx] = ((unsigned)x < (unsigned)WW) ? 1.f : 0.f;
  }

  // wave-uniform dest offset (floats) for global_load_lds
  const int wu = (t & ~63) * 4;     // 0 or 256 dwords

  // stage slice for phase p into buf: 648 float4 = 5 full-block iters + 8 tail
  auto stage = [&](int p, int bufsel) {
    const int i = p / OUTC, o = p % OUTC;
    const float* wsrc = wts + ((size_t)(((s*OUTC + o)*INC + i)*OHH + h)*OWW + wq*WQ)*KK;
    float* dst = ldsW[bufsel];
    #pragma unroll
    for (int j = 0; j < 5; ++j)
      gll16(wsrc + (size_t)(j*128 + t)*4, dst + j*512 + wu);
    if (t < 8)
      gll16(wsrc + (size_t)(640 + t)*4, dst + 2560 + wu);
  };

  float acc[OUTC] = {0.f, 0.f, 0.f};

  stage(0, 0);
  __syncthreads();   // prologue drain (exposed once)

  #pragma unroll
  for (int p = 0; p < NPH; ++p) {
    const int i = p / OUTC, o = p % OUTC;

    if (p + 1 < NPH) stage(p + 1, (p + 1) & 1);   // in flight during compute

    // ---- compute phase p from ldsW[p&1] ----
    const float* wrow = &ldsW[p & 1][wl*KK];
    const float* lfr  = lfb + (size_t)i*HWSZ;
    float a = acc[o];
    #pragma unroll
    for (int ky = 0; ky < KDIM; ++ky) {
      const int y = ybase + ky;           // block-uniform -> scalar branch
      if ((unsigned)y < (unsigned)HH) {
        const float* rowp = lfr + (size_t)y*WW;
        #pragma unroll
        for (int kx = 0; kx < KDIM; ++kx) {
          const float wv = wrow[ky*KDIM + kx];       // lane stride 81: conflict-free
          const float v  = rowp[xi[kx]] * xm[kx];
          a = fmaf(v, wv, a);
        }
      }
    }
    acc[o] = a;

    if (p + 1 < NPH) __syncthreads();   // drains vmcnt: next buffer landed; cur free
  }

  // ---- epilogue: bias + clip + coalesced stores ----
  #pragma unroll
  for (int o = 0; o < OUTC; ++o) {
    const float bv = bias[((s*OUTC + o)*OHH + h)*OWW + w];
    float r = acc[o] + bv;
    r = r < 0.f ? 0.f : (r > 1.f ? 1.f : r);
    out[(((size_t)(b*ST + s)*OUTC + o)*OHH + h)*OWW + w] = r;
  }
}

extern "C" void kernel_launch(void* const* d_in, const int* in_sizes, int n_in,
                              void* d_out, int out_size, void* d_ws, size_t ws_size,
                              hipStream_t stream) {
  const float* lf   = (const float*)d_in[0];
  const float* wts  = (const float*)d_in[1];
  const float* bias = (const float*)d_in[2];
  float* out = (float*)d_out;
  dim3 grid(ST * OHH * 4);   // 4608 blocks: (s, h, w-quarter)
  dim3 block(128);           // (w:32) x (batch:4)
  hipLaunchKernelGGL(lf_filter_kernel, grid, block, 0, stream, lf, wts, bias, out);
}